// Round 13
// baseline (502.820 us; speedup 1.0000x reference)
//
#include <hip/hip_runtime.h>
#include <hip/hip_fp16.h>
#include <stdint.h>

#define TOKENS 4096
#define HDIM   2048
#define IDIM   5632
#define BM 128
#define BN 128
#define BK 64

#define G1_NP  11264
#define G1_KSB (G1_NP * 64)    // halves per K-tile panel of Bt (gate/up)

typedef _Float16 f16x8 __attribute__((ext_vector_type(8)));
typedef float    f32x4 __attribute__((ext_vector_type(4)));

// ---------- fp4 decode helpers (verified rounds 1-12) ----------
__device__ __forceinline__ uint32_t dec2(uint32_t z, uint32_t s2u) {
    uint32_t sgn = (z << 12) & 0x80008000u;
    uint32_t h   = ((z << 9) & 0x0E000E00u) | sgn;
    __half2 hv = __builtin_bit_cast(__half2, h);
    __half2 sv = __builtin_bit_cast(__half2, s2u);
    __half2 r  = __hmul2(hv, sv);
    return __builtin_bit_cast(uint32_t, r);
}
__device__ __forceinline__ int4 dec8(uint32_t w, uint32_t s2u) {
    int4 d;
    d.x = (int)dec2( w        & 0x000F000Fu, s2u);
    d.y = (int)dec2((w >> 4)  & 0x000F000Fu, s2u);
    d.z = (int)dec2((w >> 8)  & 0x000F000Fu, s2u);
    d.w = (int)dec2((w >> 12) & 0x000F000Fu, s2u);
    return d;
}
__device__ __forceinline__ uint32_t scale_s2u(float sc) {
    uint16_t hs = __builtin_bit_cast(uint16_t, __float2half(sc * 16384.0f));
    return (uint32_t)hs * 0x00010001u;
}
__device__ __forceinline__ uint32_t packh(float lo, float hi) {
    __half2 h2 = __halves2half2(__float2half(lo), __float2half(hi));
    return __builtin_bit_cast(uint32_t, h2);
}
__device__ __forceinline__ void gl_lds16(const void* g, void* l) {
    __builtin_amdgcn_global_load_lds(
        (const __attribute__((address_space(1))) uint32_t*)g,
        (__attribute__((address_space(3))) uint32_t*)l, 16, 0, 0);
}

// ---------- hidden fp32 -> f16, sigma k-order within each 8-group ----------
__global__ __launch_bounds__(256) void convert_hidden(
    const float* __restrict__ src, __half* __restrict__ dst)
{
    int idx = blockIdx.x * 256 + threadIdx.x;   // one 8-group per thread
    const float4* s = (const float4*)src + (size_t)idx * 2;
    float4 a = s[0], b = s[1];                  // a = x0..x3, b = x4..x7
    int4 v;
    v.x = (int)packh(a.x, b.x);                 // pos 0,1 = x0,x4
    v.y = (int)packh(a.y, b.y);
    v.z = (int)packh(a.z, b.z);
    v.w = (int)packh(a.w, b.w);
    *((int4*)dst + idx) = v;
}

// ---------- dequant W_gu v7 -> f16 panels Bt[32][11264][64].
// np interleave: np = pair*64 + sel*32 + w32 (gate/up alternate by 32 cols).
// Thread <-> (np, j): wave stores one CONTIGUOUS 1 KB burst. ----------
__global__ __launch_bounds__(256) void dequant_wgu7(
    const uint32_t* __restrict__ W, const float* __restrict__ S,
    __half* __restrict__ Bt)
{
    const int kt = blockIdx.y;                       // 0..31
    const int t  = threadIdx.x;
    const int np = blockIdx.x * 32 + (t >> 3);       // interleaved row
    const int j  = t & 7;                            // k-word in tile
    const int sc = (np >> 6) * 32 + (np & 31) + (((np >> 5) & 1) ? IDIM : 0);
    uint32_t s2u = scale_s2u(S[(size_t)(kt >> 1) * (2 * IDIM) + sc]);
    uint32_t w   = W[(size_t)(kt * 8 + j) * (2 * IDIM) + sc];
    int4 d = dec8(w, s2u);
    *(int4*)(Bt + (size_t)kt * G1_KSB + (size_t)np * 64 + j * 8) = d;
}

// ---------- GEMM1 v13 (B-direct): r5's proven 2-barrier loop, but B fragments
// load global->VGPR (k-major Bt rows are dense 128 B lines, L2-resident).
// LDS holds only A (16 KB): traffic/block-K-tile 96->48 KB — the measured
// LDS-BW bottleneck (80 B/cy ~= m134's 85 B/cy ceiling) is halved.
// B loads issued before __syncthreads so L2 latency rides the staging drain. ----------
__global__ __launch_bounds__(256, 3) void gemm1_bd(
    const __half* __restrict__ A, const __half* __restrict__ Bt,
    __half* __restrict__ act)
{
    __shared__ __half Alds[BM * 64];   // 16 KB (A only)
    const int tid  = threadIdx.x;
    const int lane = tid & 63;
    const int wid  = tid >> 6;
    const int wm = wid >> 1, wn = wid & 1;
    const int m0 = blockIdx.y * BM;
    const int n0 = blockIdx.x * BN;

    f32x4 acc[4][4];
    #pragma unroll
    for (int i = 0; i < 4; ++i)
        #pragma unroll
        for (int j = 0; j < 4; ++j) acc[i][j] = f32x4{0.f, 0.f, 0.f, 0.f};

    // A staging (gl_lds, pre-swizzled source slots) — unchanged from r5
    const __half* srcA[4];
    #pragma unroll
    for (int i = 0; i < 4; ++i) {
        int u = i * 256 + tid, row = u >> 3, s = u & 7, sl = s ^ (row & 7);
        srcA[i] = A + (size_t)(m0 + row) * HDIM + sl * 8;
    }

    // B direct-load base: row = n0 + wn*64 + (lane&15), slot = lane>>4
    const __half* pB = Bt + (size_t)(n0 + wn * 64 + (lane & 15)) * 64
                          + (size_t)(lane >> 4) * 8;

    // hoisted A LDS-read byte offsets (invariant across kt)
    int aoff[4][2];
    #pragma unroll
    for (int f = 0; f < 4; ++f)
        #pragma unroll
        for (int ks = 0; ks < 2; ++ks) {
            int kb = ks * 4 + (lane >> 4);
            int ra = wm * 64 + f * 16 + (lane & 15);
            aoff[f][ks] = ra * 128 + ((kb ^ (ra & 7)) << 4);
        }

    for (int kt = 0; kt < HDIM / 64; ++kt) {
        // issue B fragment loads first (8 x dwordx4 -> VGPR, L2-resident panel)
        f16x8 bf[4][2];
        #pragma unroll
        for (int ni = 0; ni < 4; ++ni)
            #pragma unroll
            for (int ks = 0; ks < 2; ++ks)
                bf[ni][ks] = *(const f16x8*)(pB + (size_t)kt * G1_KSB + ni * 1024 + ks * 32);
        // stage A
        #pragma unroll
        for (int i = 0; i < 4; ++i) {
            int u = i * 256 + tid;
            gl_lds16(srcA[i], (char*)Alds + u * 16);
            srcA[i] += 64;
        }
        __syncthreads();
        #pragma unroll
        for (int ks = 0; ks < 2; ++ks) {
            f16x8 af[4];
            #pragma unroll
            for (int f = 0; f < 4; ++f)
                af[f] = *(const f16x8*)((const char*)Alds + aoff[f][ks]);
            #pragma unroll
            for (int mi = 0; mi < 4; ++mi)
                #pragma unroll
                for (int ni = 0; ni < 4; ++ni)
                    acc[mi][ni] = __builtin_amdgcn_mfma_f32_16x16x32_f16(af[mi], bf[ni][ks], acc[mi][ni], 0, 0, 0);
        }
        __syncthreads();
    }

    // epilogue: 32-col gate/up interleave -> ni=0,1 gate, ni=2,3 up; sigma slot
    const int pairbase = ((n0 + wn * 64) >> 6) * 32;
    #pragma unroll
    for (int mi = 0; mi < 4; ++mi) {
        #pragma unroll
        for (int q = 0; q < 2; ++q) {
            int gcol = pairbase + q * 16 + (lane & 15);
            int colstore = (gcol & ~7) | (((gcol & 3) << 1) | ((gcol >> 2) & 1));
            #pragma unroll
            for (int r = 0; r < 4; ++r) {
                int m = m0 + wm * 64 + mi * 16 + (lane >> 4) * 4 + r;
                float gv = acc[mi][q][r];
                float uv = acc[mi][q + 2][r];
                float sig = 1.0f / (1.0f + __expf(-gv));
                act[(size_t)m * IDIM + colstore] = __float2half(gv * sig * uv);
            }
        }
    }
}

// ---------- round-1 fused-decode GEMM1 (fallback if ws too small) ----------
__global__ __launch_bounds__(256, 2) void gemm1_silu(
    const __half* __restrict__ A, const uint32_t* __restrict__ W,
    const float* __restrict__ S, __half* __restrict__ act)
{
    __shared__ __half Alds[BM * BK];
    __shared__ __half Blds[2][BN * BK];
    const int tid  = threadIdx.x;
    const int lane = tid & 63;
    const int wid  = tid >> 6;
    const int wm = wid >> 1, wn = wid & 1;
    const int m0 = blockIdx.y * BM;
    const int c0 = blockIdx.x * BN;

    f32x4 accg[4][4], accu[4][4];
    #pragma unroll
    for (int i = 0; i < 4; ++i)
        #pragma unroll
        for (int j = 0; j < 4; ++j) {
            accg[i][j] = f32x4{0.f, 0.f, 0.f, 0.f};
            accu[i][j] = f32x4{0.f, 0.f, 0.f, 0.f};
        }

    const int c = tid & 127;
    const int rbase = (tid >> 7) * 4;

    for (int kt = 0; kt < HDIM / BK; ++kt) {
        const int k0 = kt * BK;
        #pragma unroll
        for (int i = 0; i < 4; ++i) {
            int u = tid + i * 256;
            int row = u >> 3, kb = u & 7;
            int4 v = *(const int4*)(A + (size_t)(m0 + row) * HDIM + k0 + kb * 8);
            *(int4*)((char*)Alds + row * 128 + ((kb ^ (row & 7)) << 4)) = v;
        }
        const int g = k0 >> 7;
        #pragma unroll
        for (int p = 0; p < 2; ++p) {
            const int ncol = (p ? IDIM : 0) + c0 + c;
            uint32_t s2u = scale_s2u(S[(size_t)g * (2 * IDIM) + ncol]);
            #pragma unroll
            for (int i = 0; i < 4; ++i) {
                int rl = rbase + i;
                uint32_t w = W[(size_t)(kt * 8 + rl) * (2 * IDIM) + ncol];
                int4 d = dec8(w, s2u);
                *(int4*)((char*)&Blds[p][0] + c * 128 + ((rl ^ (c & 7)) << 4)) = d;
            }
        }
        __syncthreads();
        #pragma unroll
        for (int ks = 0; ks < 2; ++ks) {
            f16x8 af[4], bg[4], bu[4];
            const int kb = ks * 4 + (lane >> 4);
            #pragma unroll
            for (int mi = 0; mi < 4; ++mi) {
                int m = wm * 64 + mi * 16 + (lane & 15);
                af[mi] = *(const f16x8*)((const char*)Alds + m * 128 + ((kb ^ (m & 7)) << 4));
            }
            #pragma unroll
            for (int ni = 0; ni < 4; ++ni) {
                int n = wn * 64 + ni * 16 + (lane & 15);
                bg[ni] = *(const f16x8*)((const char*)&Blds[0][0] + n * 128 + ((kb ^ (n & 7)) << 4));
                bu[ni] = *(const f16x8*)((const char*)&Blds[1][0] + n * 128 + ((kb ^ (n & 7)) << 4));
            }
            #pragma unroll
            for (int mi = 0; mi < 4; ++mi)
                #pragma unroll
                for (int ni = 0; ni < 4; ++ni) {
                    accg[mi][ni] = __builtin_amdgcn_mfma_f32_16x16x32_f16(af[mi], bg[ni], accg[mi][ni], 0, 0, 0);
                    accu[mi][ni] = __builtin_amdgcn_mfma_f32_16x16x32_f16(af[mi], bu[ni], accu[mi][ni], 0, 0, 0);
                }
        }
        __syncthreads();
    }
    #pragma unroll
    for (int mi = 0; mi < 4; ++mi) {
        #pragma unroll
        for (int ni = 0; ni < 4; ++ni) {
            int nlog = c0 + wn * 64 + ni * 16 + (lane & 15);
            int ncol = (nlog & ~7) | (((nlog & 3) << 1) | ((nlog >> 2) & 1));
            #pragma unroll
            for (int r = 0; r < 4; ++r) {
                int m = m0 + wm * 64 + mi * 16 + (lane >> 4) * 4 + r;
                float gv = accg[mi][ni][r];
                float uv = accu[mi][ni][r];
                float sig = 1.0f / (1.0f + __expf(-gv));
                act[(size_t)m * IDIM + ncol] = __float2half(gv * sig * uv);
            }
        }
    }
}

// ---------- GEMM2 (fused decode, proven ~90 us, 2D grid) ----------
__global__ __launch_bounds__(256, 2) void gemm2_add(
    const __half* __restrict__ A, const uint32_t* __restrict__ W,
    const float* __restrict__ S, const float* __restrict__ moe,
    float* __restrict__ out)
{
    __shared__ __half Alds[BM * BK];
    __shared__ __half Blds[BN * BK];
    const int tid  = threadIdx.x;
    const int lane = tid & 63;
    const int wid  = tid >> 6;
    const int wm = wid >> 1, wn = wid & 1;
    const int m0 = blockIdx.y * BM;
    const int n0 = blockIdx.x * BN;

    f32x4 acc[4][4];
    #pragma unroll
    for (int i = 0; i < 4; ++i)
        #pragma unroll
        for (int j = 0; j < 4; ++j) acc[i][j] = f32x4{0.f, 0.f, 0.f, 0.f};

    const int c = tid & 127;
    const int rbase = (tid >> 7) * 4;

    int aoff[4][2], boff[4][2];
    #pragma unroll
    for (int f = 0; f < 4; ++f)
        #pragma unroll
        for (int ks = 0; ks < 2; ++ks) {
            int kb = ks * 4 + (lane >> 4);
            int ra = wm * 64 + f * 16 + (lane & 15);
            int rb = wn * 64 + f * 16 + (lane & 15);
            aoff[f][ks] = ra * 128 + ((kb ^ (ra & 7)) << 4);
            boff[f][ks] = rb * 128 + ((kb ^ (rb & 7)) << 4);
        }

    for (int kt = 0; kt < IDIM / BK; ++kt) {
        const int k0 = kt * BK;
        #pragma unroll
        for (int i = 0; i < 4; ++i) {
            int u = tid + i * 256;
            int row = u >> 3, kb = u & 7;
            int4 v = *(const int4*)(A + (size_t)(m0 + row) * IDIM + k0 + kb * 8);
            *(int4*)((char*)Alds + row * 128 + ((kb ^ (row & 7)) << 4)) = v;
        }
        {
            const int g = k0 >> 7;
            const int ncol = n0 + c;
            uint32_t s2u = scale_s2u(S[(size_t)g * HDIM + ncol]);
            #pragma unroll
            for (int i = 0; i < 4; ++i) {
                int rl = rbase + i;
                uint32_t w = W[(size_t)(kt * 8 + rl) * HDIM + ncol];
                int4 d = dec8(w, s2u);
                *(int4*)((char*)Blds + c * 128 + ((rl ^ (c & 7)) << 4)) = d;
            }
        }
        __syncthreads();
        #pragma unroll
        for (int ks = 0; ks < 2; ++ks) {
            f16x8 af[4], bf[4];
            #pragma unroll
            for (int f = 0; f < 4; ++f) {
                af[f] = *(const f16x8*)((const char*)Alds + aoff[f][ks]);
                bf[f] = *(const f16x8*)((const char*)Blds + boff[f][ks]);
            }
            #pragma unroll
            for (int mi = 0; mi < 4; ++mi)
                #pragma unroll
                for (int ni = 0; ni < 4; ++ni)
                    acc[mi][ni] = __builtin_amdgcn_mfma_f32_16x16x32_f16(af[mi], bf[ni], acc[mi][ni], 0, 0, 0);
        }
        __syncthreads();
    }
    #pragma unroll
    for (int mi = 0; mi < 4; ++mi) {
        #pragma unroll
        for (int ni = 0; ni < 4; ++ni) {
            int n = n0 + wn * 64 + ni * 16 + (lane & 15);
            #pragma unroll
            for (int r = 0; r < 4; ++r) {
                int m = m0 + wm * 64 + mi * 16 + (lane >> 4) * 4 + r;
                out[(size_t)m * HDIM + n] = moe[(size_t)m * HDIM + n] + acc[mi][ni][r];
            }
        }
    }
}

extern "C" void kernel_launch(void* const* d_in, const int* in_sizes, int n_in,
                              void* d_out, int out_size, void* d_ws, size_t ws_size,
                              hipStream_t stream) {
    const float*    hidden = (const float*)d_in[0];
    const float*    moe    = (const float*)d_in[1];
    const uint32_t* wgu    = (const uint32_t*)d_in[2];
    const float*    sgu    = (const float*)d_in[3];
    const uint32_t* wd     = (const uint32_t*)d_in[4];
    const float*    sd     = (const float*)d_in[5];
    float* out = (float*)d_out;

    const size_t sz_hidden = (size_t)TOKENS * HDIM * 2;      // 16.78 MB
    const size_t sz_act    = (size_t)TOKENS * IDIM * 2;      // 46.14 MB
    const size_t sz_wgu16  = (size_t)HDIM * 2 * IDIM * 2;    // 46.14 MB

    __half* hidden_f16 = (__half*)d_ws;
    __half* act        = (__half*)((char*)d_ws + sz_hidden);
    __half* wgu16      = (__half*)((char*)d_ws + sz_hidden + sz_act);

    const size_t need_g1 = sz_hidden + sz_act + sz_wgu16;    // 109 MB (available r5-r12)

    convert_hidden<<<dim3(TOKENS * HDIM / 8 / 256), dim3(256), 0, stream>>>(hidden, hidden_f16);

    if (ws_size >= need_g1) {
        dequant_wgu7<<<dim3(G1_NP / 32, 32), dim3(256), 0, stream>>>(wgu, sgu, wgu16);
        gemm1_bd<<<dim3(G1_NP / BN, TOKENS / BM), dim3(256), 0, stream>>>(hidden_f16, wgu16, act);
    } else {
        gemm1_silu<<<dim3(IDIM / BN, TOKENS / BM), dim3(256), 0, stream>>>(hidden_f16, wgu, sgu, act);
    }

    gemm2_add<<<dim3(HDIM / BN, TOKENS / BM), dim3(256), 0, stream>>>(act, wd, sd, moe, out);
}

// Round 14
// 336.138 us; speedup vs baseline: 1.4959x; 1.4959x over previous
//
#include <hip/hip_runtime.h>
#include <hip/hip_fp16.h>
#include <stdint.h>

#define TOKENS 4096
#define HDIM   2048
#define IDIM   5632
#define BM 128
#define BN 128
#define BK 64

#define G1_NP  11264
#define G1_KSB (G1_NP * 64)    // halves per K-tile panel of Bt (gate/up)

typedef _Float16 f16x8 __attribute__((ext_vector_type(8)));
typedef float    f32x4 __attribute__((ext_vector_type(4)));

// ---------- fp4 decode helpers (verified rounds 1-13) ----------
__device__ __forceinline__ uint32_t dec2(uint32_t z, uint32_t s2u) {
    uint32_t sgn = (z << 12) & 0x80008000u;
    uint32_t h   = ((z << 9) & 0x0E000E00u) | sgn;
    __half2 hv = __builtin_bit_cast(__half2, h);
    __half2 sv = __builtin_bit_cast(__half2, s2u);
    __half2 r  = __hmul2(hv, sv);
    return __builtin_bit_cast(uint32_t, r);
}
__device__ __forceinline__ int4 dec8(uint32_t w, uint32_t s2u) {
    int4 d;
    d.x = (int)dec2( w        & 0x000F000Fu, s2u);
    d.y = (int)dec2((w >> 4)  & 0x000F000Fu, s2u);
    d.z = (int)dec2((w >> 8)  & 0x000F000Fu, s2u);
    d.w = (int)dec2((w >> 12) & 0x000F000Fu, s2u);
    return d;
}
__device__ __forceinline__ uint32_t scale_s2u(float sc) {
    uint16_t hs = __builtin_bit_cast(uint16_t, __float2half(sc * 16384.0f));
    return (uint32_t)hs * 0x00010001u;
}
__device__ __forceinline__ uint32_t packh(float lo, float hi) {
    __half2 h2 = __halves2half2(__float2half(lo), __float2half(hi));
    return __builtin_bit_cast(uint32_t, h2);
}
__device__ __forceinline__ void gl_lds16(const void* g, void* l) {
    __builtin_amdgcn_global_load_lds(
        (const __attribute__((address_space(1))) uint32_t*)g,
        (__attribute__((address_space(3))) uint32_t*)l, 16, 0, 0);
}

// ---------- hidden fp32 -> f16, sigma k-order within each 8-group ----------
__global__ __launch_bounds__(256) void convert_hidden(
    const float* __restrict__ src, __half* __restrict__ dst)
{
    int idx = blockIdx.x * 256 + threadIdx.x;   // one 8-group per thread
    const float4* s = (const float4*)src + (size_t)idx * 2;
    float4 a = s[0], b = s[1];                  // a = x0..x3, b = x4..x7
    int4 v;
    v.x = (int)packh(a.x, b.x);                 // pos 0,1 = x0,x4
    v.y = (int)packh(a.y, b.y);
    v.z = (int)packh(a.z, b.z);
    v.w = (int)packh(a.w, b.w);
    *((int4*)dst + idx) = v;
}

// ---------- dequant W_gu v4 mapping, 32-col interleave ->
// Bt[32][11264][64]. Thread <-> interleaved row np (np = pair*64 + sel*32 +
// w32), j-loop inside: per-instruction reads are lane-consecutive sc words
// (coalesced); stores are 8 x 16B per thread filling one 128 B line
// (temporally adjacent -> L2 merges). Measured-best dequant (~14 us, r6). ----------
__global__ __launch_bounds__(256) void dequant_wgu4(
    const uint32_t* __restrict__ W, const float* __restrict__ S,
    __half* __restrict__ Bt)
{
    const int kt = blockIdx.y;                       // 0..31
    const int np = blockIdx.x * 256 + threadIdx.x;   // interleaved row 0..11263
    const int sc = (np >> 6) * 32 + (np & 31) + (((np >> 5) & 1) ? IDIM : 0);
    uint32_t s2u = scale_s2u(S[(size_t)(kt >> 1) * (2 * IDIM) + sc]);
    __half* dst = Bt + (size_t)kt * G1_KSB + (size_t)np * 64;
    #pragma unroll
    for (int j = 0; j < 8; ++j) {
        uint32_t w = W[(size_t)(kt * 8 + j) * (2 * IDIM) + sc];
        int4 d = dec8(w, s2u);
        *(int4*)(dst + j * 8) = d;
    }
}

// ---------- GEMM1: r11's measured kernel (175.5 us, 53% MfmaUtil, 0 conflicts).
// 128x128 tile, 256 thr, 4 waves (64x64), single-buffer 32 KB LDS, gl_lds
// staging with per-lane source swizzle, hoisted LDS-read offsets.
// Epilogue: 32-col gate/up interleave (ni=0,1 gate / ni=2,3 up). ----------
__global__ __launch_bounds__(256, 4) void gemm1_s(
    const __half* __restrict__ A, const __half* __restrict__ Bt,
    __half* __restrict__ act)
{
    __shared__ __half Alds[BM * 64];   // 16 KB
    __shared__ __half Blds[BN * 64];   // 16 KB
    const int tid  = threadIdx.x;
    const int lane = tid & 63;
    const int wid  = tid >> 6;
    const int wm = wid >> 1, wn = wid & 1;
    const int m0 = blockIdx.y * BM;
    const int n0 = blockIdx.x * BN;

    f32x4 acc[4][4];
    #pragma unroll
    for (int i = 0; i < 4; ++i)
        #pragma unroll
        for (int j = 0; j < 4; ++j) acc[i][j] = f32x4{0.f, 0.f, 0.f, 0.f};

    const __half* srcA[4];
    const __half* srcB[4];
    #pragma unroll
    for (int i = 0; i < 4; ++i) {
        int u = i * 256 + tid, row = u >> 3, s = u & 7, sl = s ^ (row & 7);
        srcA[i] = A  + (size_t)(m0 + row) * HDIM + sl * 8;
        srcB[i] = Bt + (size_t)(n0 + row) * 64 + sl * 8;
    }

    // hoisted LDS-read byte offsets (invariant across kt)
    int aoff[4][2], boff[4][2];
    #pragma unroll
    for (int f = 0; f < 4; ++f)
        #pragma unroll
        for (int ks = 0; ks < 2; ++ks) {
            int kb = ks * 4 + (lane >> 4);
            int ra = wm * 64 + f * 16 + (lane & 15);
            int rb = wn * 64 + f * 16 + (lane & 15);
            aoff[f][ks] = ra * 128 + ((kb ^ (ra & 7)) << 4);
            boff[f][ks] = rb * 128 + ((kb ^ (rb & 7)) << 4);
        }

    for (int kt = 0; kt < HDIM / 64; ++kt) {
        #pragma unroll
        for (int i = 0; i < 4; ++i) {
            int u = i * 256 + tid;
            gl_lds16(srcA[i], (char*)Alds + u * 16);
            gl_lds16(srcB[i], (char*)Blds + u * 16);
            srcA[i] += 64;
            srcB[i] += G1_KSB;
        }
        __syncthreads();
        #pragma unroll
        for (int ks = 0; ks < 2; ++ks) {
            f16x8 af[4], bf[4];
            #pragma unroll
            for (int f = 0; f < 4; ++f) {
                af[f] = *(const f16x8*)((const char*)Alds + aoff[f][ks]);
                bf[f] = *(const f16x8*)((const char*)Blds + boff[f][ks]);
            }
            #pragma unroll
            for (int mi = 0; mi < 4; ++mi)
                #pragma unroll
                for (int ni = 0; ni < 4; ++ni)
                    acc[mi][ni] = __builtin_amdgcn_mfma_f32_16x16x32_f16(af[mi], bf[ni], acc[mi][ni], 0, 0, 0);
        }
        __syncthreads();
    }

    // epilogue: 32-col interleave -> ni=0,1 gate cols, ni=2,3 up cols. sigma slot.
    const int pairbase = ((n0 + wn * 64) >> 6) * 32;
    #pragma unroll
    for (int mi = 0; mi < 4; ++mi) {
        #pragma unroll
        for (int q = 0; q < 2; ++q) {
            int gcol = pairbase + q * 16 + (lane & 15);
            int colstore = (gcol & ~7) | (((gcol & 3) << 1) | ((gcol >> 2) & 1));
            #pragma unroll
            for (int r = 0; r < 4; ++r) {
                int m = m0 + wm * 64 + mi * 16 + (lane >> 4) * 4 + r;
                float gv = acc[mi][q][r];
                float uv = acc[mi][q + 2][r];
                float sig = 1.0f / (1.0f + __expf(-gv));
                act[(size_t)m * IDIM + colstore] = __float2half(gv * sig * uv);
            }
        }
    }
}

// ---------- round-1 fused-decode GEMM1 (fallback if ws too small) ----------
__global__ __launch_bounds__(256, 2) void gemm1_silu(
    const __half* __restrict__ A, const uint32_t* __restrict__ W,
    const float* __restrict__ S, __half* __restrict__ act)
{
    __shared__ __half Alds[BM * BK];
    __shared__ __half Blds[2][BN * BK];
    const int tid  = threadIdx.x;
    const int lane = tid & 63;
    const int wid  = tid >> 6;
    const int wm = wid >> 1, wn = wid & 1;
    const int m0 = blockIdx.y * BM;
    const int c0 = blockIdx.x * BN;

    f32x4 accg[4][4], accu[4][4];
    #pragma unroll
    for (int i = 0; i < 4; ++i)
        #pragma unroll
        for (int j = 0; j < 4; ++j) {
            accg[i][j] = f32x4{0.f, 0.f, 0.f, 0.f};
            accu[i][j] = f32x4{0.f, 0.f, 0.f, 0.f};
        }

    const int c = tid & 127;
    const int rbase = (tid >> 7) * 4;

    for (int kt = 0; kt < HDIM / BK; ++kt) {
        const int k0 = kt * BK;
        #pragma unroll
        for (int i = 0; i < 4; ++i) {
            int u = tid + i * 256;
            int row = u >> 3, kb = u & 7;
            int4 v = *(const int4*)(A + (size_t)(m0 + row) * HDIM + k0 + kb * 8);
            *(int4*)((char*)Alds + row * 128 + ((kb ^ (row & 7)) << 4)) = v;
        }
        const int g = k0 >> 7;
        #pragma unroll
        for (int p = 0; p < 2; ++p) {
            const int ncol = (p ? IDIM : 0) + c0 + c;
            uint32_t s2u = scale_s2u(S[(size_t)g * (2 * IDIM) + ncol]);
            #pragma unroll
            for (int i = 0; i < 4; ++i) {
                int rl = rbase + i;
                uint32_t w = W[(size_t)(kt * 8 + rl) * (2 * IDIM) + ncol];
                int4 d = dec8(w, s2u);
                *(int4*)((char*)&Blds[p][0] + c * 128 + ((rl ^ (c & 7)) << 4)) = d;
            }
        }
        __syncthreads();
        #pragma unroll
        for (int ks = 0; ks < 2; ++ks) {
            f16x8 af[4], bg[4], bu[4];
            const int kb = ks * 4 + (lane >> 4);
            #pragma unroll
            for (int mi = 0; mi < 4; ++mi) {
                int m = wm * 64 + mi * 16 + (lane & 15);
                af[mi] = *(const f16x8*)((const char*)Alds + m * 128 + ((kb ^ (m & 7)) << 4));
            }
            #pragma unroll
            for (int ni = 0; ni < 4; ++ni) {
                int n = wn * 64 + ni * 16 + (lane & 15);
                bg[ni] = *(const f16x8*)((const char*)&Blds[0][0] + n * 128 + ((kb ^ (n & 7)) << 4));
                bu[ni] = *(const f16x8*)((const char*)&Blds[1][0] + n * 128 + ((kb ^ (n & 7)) << 4));
            }
            #pragma unroll
            for (int mi = 0; mi < 4; ++mi)
                #pragma unroll
                for (int ni = 0; ni < 4; ++ni) {
                    accg[mi][ni] = __builtin_amdgcn_mfma_f32_16x16x32_f16(af[mi], bg[ni], accg[mi][ni], 0, 0, 0);
                    accu[mi][ni] = __builtin_amdgcn_mfma_f32_16x16x32_f16(af[mi], bu[ni], accu[mi][ni], 0, 0, 0);
                }
        }
        __syncthreads();
    }
    #pragma unroll
    for (int mi = 0; mi < 4; ++mi) {
        #pragma unroll
        for (int ni = 0; ni < 4; ++ni) {
            int nlog = c0 + wn * 64 + ni * 16 + (lane & 15);
            int ncol = (nlog & ~7) | (((nlog & 3) << 1) | ((nlog >> 2) & 1));
            #pragma unroll
            for (int r = 0; r < 4; ++r) {
                int m = m0 + wm * 64 + mi * 16 + (lane >> 4) * 4 + r;
                float gv = accg[mi][ni][r];
                float uv = accu[mi][ni][r];
                float sig = 1.0f / (1.0f + __expf(-gv));
                act[(size_t)m * IDIM + ncol] = __float2half(gv * sig * uv);
            }
        }
    }
}

// ---------- GEMM2 (fused decode, r5/r8 measured ~83-90 us, no hoist) ----------
__global__ __launch_bounds__(256, 2) void gemm2_add(
    const __half* __restrict__ A, const uint32_t* __restrict__ W,
    const float* __restrict__ S, const float* __restrict__ moe,
    float* __restrict__ out)
{
    __shared__ __half Alds[BM * BK];
    __shared__ __half Blds[BN * BK];
    const int tid  = threadIdx.x;
    const int lane = tid & 63;
    const int wid  = tid >> 6;
    const int wm = wid >> 1, wn = wid & 1;
    const int m0 = blockIdx.y * BM;
    const int n0 = blockIdx.x * BN;

    f32x4 acc[4][4];
    #pragma unroll
    for (int i = 0; i < 4; ++i)
        #pragma unroll
        for (int j = 0; j < 4; ++j) acc[i][j] = f32x4{0.f, 0.f, 0.f, 0.f};

    const int c = tid & 127;
    const int rbase = (tid >> 7) * 4;

    for (int kt = 0; kt < IDIM / BK; ++kt) {
        const int k0 = kt * BK;
        #pragma unroll
        for (int i = 0; i < 4; ++i) {
            int u = tid + i * 256;
            int row = u >> 3, kb = u & 7;
            int4 v = *(const int4*)(A + (size_t)(m0 + row) * IDIM + k0 + kb * 8);
            *(int4*)((char*)Alds + row * 128 + ((kb ^ (row & 7)) << 4)) = v;
        }
        {
            const int g = k0 >> 7;
            const int ncol = n0 + c;
            uint32_t s2u = scale_s2u(S[(size_t)g * HDIM + ncol]);
            #pragma unroll
            for (int i = 0; i < 4; ++i) {
                int rl = rbase + i;
                uint32_t w = W[(size_t)(kt * 8 + rl) * HDIM + ncol];
                int4 d = dec8(w, s2u);
                *(int4*)((char*)Blds + c * 128 + ((rl ^ (c & 7)) << 4)) = d;
            }
        }
        __syncthreads();
        #pragma unroll
        for (int ks = 0; ks < 2; ++ks) {
            f16x8 af[4], bf[4];
            const int kb = ks * 4 + (lane >> 4);
            #pragma unroll
            for (int mi = 0; mi < 4; ++mi) {
                int m = wm * 64 + mi * 16 + (lane & 15);
                af[mi] = *(const f16x8*)((const char*)Alds + m * 128 + ((kb ^ (m & 7)) << 4));
            }
            #pragma unroll
            for (int ni = 0; ni < 4; ++ni) {
                int n = wn * 64 + ni * 16 + (lane & 15);
                bf[ni] = *(const f16x8*)((const char*)Blds + n * 128 + ((kb ^ (n & 7)) << 4));
            }
            #pragma unroll
            for (int mi = 0; mi < 4; ++mi)
                #pragma unroll
                for (int ni = 0; ni < 4; ++ni)
                    acc[mi][ni] = __builtin_amdgcn_mfma_f32_16x16x32_f16(af[mi], bf[ni], acc[mi][ni], 0, 0, 0);
        }
        __syncthreads();
    }
    #pragma unroll
    for (int mi = 0; mi < 4; ++mi) {
        #pragma unroll
        for (int ni = 0; ni < 4; ++ni) {
            int n = n0 + wn * 64 + ni * 16 + (lane & 15);
            #pragma unroll
            for (int r = 0; r < 4; ++r) {
                int m = m0 + wm * 64 + mi * 16 + (lane >> 4) * 4 + r;
                out[(size_t)m * HDIM + n] = moe[(size_t)m * HDIM + n] + acc[mi][ni][r];
            }
        }
    }
}

extern "C" void kernel_launch(void* const* d_in, const int* in_sizes, int n_in,
                              void* d_out, int out_size, void* d_ws, size_t ws_size,
                              hipStream_t stream) {
    const float*    hidden = (const float*)d_in[0];
    const float*    moe    = (const float*)d_in[1];
    const uint32_t* wgu    = (const uint32_t*)d_in[2];
    const float*    sgu    = (const float*)d_in[3];
    const uint32_t* wd     = (const uint32_t*)d_in[4];
    const float*    sd     = (const float*)d_in[5];
    float* out = (float*)d_out;

    const size_t sz_hidden = (size_t)TOKENS * HDIM * 2;      // 16.78 MB
    const size_t sz_act    = (size_t)TOKENS * IDIM * 2;      // 46.14 MB
    const size_t sz_wgu16  = (size_t)HDIM * 2 * IDIM * 2;    // 46.14 MB

    __half* hidden_f16 = (__half*)d_ws;
    __half* act        = (__half*)((char*)d_ws + sz_hidden);
    __half* wgu16      = (__half*)((char*)d_ws + sz_hidden + sz_act);

    const size_t need_g1 = sz_hidden + sz_act + sz_wgu16;    // 109 MB (available r5-r13)

    convert_hidden<<<dim3(TOKENS * HDIM / 8 / 256), dim3(256), 0, stream>>>(hidden, hidden_f16);

    if (ws_size >= need_g1) {
        dequant_wgu4<<<dim3(G1_NP / 256, 32), dim3(256), 0, stream>>>(wgu, sgu, wgu16);
        gemm1_s<<<dim3(G1_NP / BN, TOKENS / BM), dim3(256), 0, stream>>>(hidden_f16, wgu16, act);
    } else {
        gemm1_silu<<<dim3(IDIM / BN, TOKENS / BM), dim3(256), 0, stream>>>(hidden_f16, wgu, sgu, act);
    }

    gemm2_add<<<dim3(HDIM / BN, TOKENS / BM), dim3(256), 0, stream>>>(act, wd, sd, moe, out);
}

// Round 15
// 334.708 us; speedup vs baseline: 1.5023x; 1.0043x over previous
//
#include <hip/hip_runtime.h>
#include <hip/hip_fp16.h>
#include <stdint.h>

#define TOKENS 4096
#define HDIM   2048
#define IDIM   5632
#define BM 128
#define BN 128
#define BK 64

#define G1_NP  11264
#define G1_KSB (G1_NP * 64)    // halves per K-tile panel of Bt (gate/up)

typedef _Float16 f16x8 __attribute__((ext_vector_type(8)));
typedef float    f32x4 __attribute__((ext_vector_type(4)));

// ---------- fp4 decode helpers (verified rounds 1-13) ----------
__device__ __forceinline__ uint32_t dec2(uint32_t z, uint32_t s2u) {
    uint32_t sgn = (z << 12) & 0x80008000u;
    uint32_t h   = ((z << 9) & 0x0E000E00u) | sgn;
    __half2 hv = __builtin_bit_cast(__half2, h);
    __half2 sv = __builtin_bit_cast(__half2, s2u);
    __half2 r  = __hmul2(hv, sv);
    return __builtin_bit_cast(uint32_t, r);
}
__device__ __forceinline__ int4 dec8(uint32_t w, uint32_t s2u) {
    int4 d;
    d.x = (int)dec2( w        & 0x000F000Fu, s2u);
    d.y = (int)dec2((w >> 4)  & 0x000F000Fu, s2u);
    d.z = (int)dec2((w >> 8)  & 0x000F000Fu, s2u);
    d.w = (int)dec2((w >> 12) & 0x000F000Fu, s2u);
    return d;
}
__device__ __forceinline__ uint32_t scale_s2u(float sc) {
    uint16_t hs = __builtin_bit_cast(uint16_t, __float2half(sc * 16384.0f));
    return (uint32_t)hs * 0x00010001u;
}
__device__ __forceinline__ uint32_t packh(float lo, float hi) {
    __half2 h2 = __halves2half2(__float2half(lo), __float2half(hi));
    return __builtin_bit_cast(uint32_t, h2);
}
__device__ __forceinline__ void gl_lds16(const void* g, void* l) {
    __builtin_amdgcn_global_load_lds(
        (const __attribute__((address_space(1))) uint32_t*)g,
        (__attribute__((address_space(3))) uint32_t*)l, 16, 0, 0);
}

// ---------- hidden fp32 -> f16, sigma k-order within each 8-group ----------
__global__ __launch_bounds__(256) void convert_hidden(
    const float* __restrict__ src, __half* __restrict__ dst)
{
    int idx = blockIdx.x * 256 + threadIdx.x;   // one 8-group per thread
    const float4* s = (const float4*)src + (size_t)idx * 2;
    float4 a = s[0], b = s[1];                  // a = x0..x3, b = x4..x7
    int4 v;
    v.x = (int)packh(a.x, b.x);                 // pos 0,1 = x0,x4
    v.y = (int)packh(a.y, b.y);
    v.z = (int)packh(a.z, b.z);
    v.w = (int)packh(a.w, b.w);
    *((int4*)dst + idx) = v;
}

// ---------- dequant W_gu v4 mapping, 32-col interleave ->
// Bt[32][11264][64]. Thread <-> interleaved row np (np = pair*64 + sel*32 +
// w32), j-loop inside: per-instruction reads are lane-consecutive sc words
// (coalesced); stores are 8 x 16B per thread filling one 128 B line
// (temporally adjacent -> L2 merges). Measured-best dequant (~14 us, r6). ----------
__global__ __launch_bounds__(256) void dequant_wgu4(
    const uint32_t* __restrict__ W, const float* __restrict__ S,
    __half* __restrict__ Bt)
{
    const int kt = blockIdx.y;                       // 0..31
    const int np = blockIdx.x * 256 + threadIdx.x;   // interleaved row 0..11263
    const int sc = (np >> 6) * 32 + (np & 31) + (((np >> 5) & 1) ? IDIM : 0);
    uint32_t s2u = scale_s2u(S[(size_t)(kt >> 1) * (2 * IDIM) + sc]);
    __half* dst = Bt + (size_t)kt * G1_KSB + (size_t)np * 64;
    #pragma unroll
    for (int j = 0; j < 8; ++j) {
        uint32_t w = W[(size_t)(kt * 8 + j) * (2 * IDIM) + sc];
        int4 d = dec8(w, s2u);
        *(int4*)(dst + j * 8) = d;
    }
}

// ---------- GEMM1: r11's measured kernel (175.5 us, 53% MfmaUtil, 0 conflicts).
// 128x128 tile, 256 thr, 4 waves (64x64), single-buffer 32 KB LDS, gl_lds
// staging with per-lane source swizzle, hoisted LDS-read offsets.
// Epilogue: 32-col gate/up interleave (ni=0,1 gate / ni=2,3 up). ----------
__global__ __launch_bounds__(256, 4) void gemm1_s(
    const __half* __restrict__ A, const __half* __restrict__ Bt,
    __half* __restrict__ act)
{
    __shared__ __half Alds[BM * 64];   // 16 KB
    __shared__ __half Blds[BN * 64];   // 16 KB
    const int tid  = threadIdx.x;
    const int lane = tid & 63;
    const int wid  = tid >> 6;
    const int wm = wid >> 1, wn = wid & 1;
    const int m0 = blockIdx.y * BM;
    const int n0 = blockIdx.x * BN;

    f32x4 acc[4][4];
    #pragma unroll
    for (int i = 0; i < 4; ++i)
        #pragma unroll
        for (int j = 0; j < 4; ++j) acc[i][j] = f32x4{0.f, 0.f, 0.f, 0.f};

    const __half* srcA[4];
    const __half* srcB[4];
    #pragma unroll
    for (int i = 0; i < 4; ++i) {
        int u = i * 256 + tid, row = u >> 3, s = u & 7, sl = s ^ (row & 7);
        srcA[i] = A  + (size_t)(m0 + row) * HDIM + sl * 8;
        srcB[i] = Bt + (size_t)(n0 + row) * 64 + sl * 8;
    }

    // hoisted LDS-read byte offsets (invariant across kt)
    int aoff[4][2], boff[4][2];
    #pragma unroll
    for (int f = 0; f < 4; ++f)
        #pragma unroll
        for (int ks = 0; ks < 2; ++ks) {
            int kb = ks * 4 + (lane >> 4);
            int ra = wm * 64 + f * 16 + (lane & 15);
            int rb = wn * 64 + f * 16 + (lane & 15);
            aoff[f][ks] = ra * 128 + ((kb ^ (ra & 7)) << 4);
            boff[f][ks] = rb * 128 + ((kb ^ (rb & 7)) << 4);
        }

    for (int kt = 0; kt < HDIM / 64; ++kt) {
        #pragma unroll
        for (int i = 0; i < 4; ++i) {
            int u = i * 256 + tid;
            gl_lds16(srcA[i], (char*)Alds + u * 16);
            gl_lds16(srcB[i], (char*)Blds + u * 16);
            srcA[i] += 64;
            srcB[i] += G1_KSB;
        }
        __syncthreads();
        #pragma unroll
        for (int ks = 0; ks < 2; ++ks) {
            f16x8 af[4], bf[4];
            #pragma unroll
            for (int f = 0; f < 4; ++f) {
                af[f] = *(const f16x8*)((const char*)Alds + aoff[f][ks]);
                bf[f] = *(const f16x8*)((const char*)Blds + boff[f][ks]);
            }
            #pragma unroll
            for (int mi = 0; mi < 4; ++mi)
                #pragma unroll
                for (int ni = 0; ni < 4; ++ni)
                    acc[mi][ni] = __builtin_amdgcn_mfma_f32_16x16x32_f16(af[mi], bf[ni], acc[mi][ni], 0, 0, 0);
        }
        __syncthreads();
    }

    // epilogue: 32-col interleave -> ni=0,1 gate cols, ni=2,3 up cols. sigma slot.
    const int pairbase = ((n0 + wn * 64) >> 6) * 32;
    #pragma unroll
    for (int mi = 0; mi < 4; ++mi) {
        #pragma unroll
        for (int q = 0; q < 2; ++q) {
            int gcol = pairbase + q * 16 + (lane & 15);
            int colstore = (gcol & ~7) | (((gcol & 3) << 1) | ((gcol >> 2) & 1));
            #pragma unroll
            for (int r = 0; r < 4; ++r) {
                int m = m0 + wm * 64 + mi * 16 + (lane >> 4) * 4 + r;
                float gv = acc[mi][q][r];
                float uv = acc[mi][q + 2][r];
                float sig = 1.0f / (1.0f + __expf(-gv));
                act[(size_t)m * IDIM + colstore] = __float2half(gv * sig * uv);
            }
        }
    }
}

// ---------- round-1 fused-decode GEMM1 (fallback if ws too small) ----------
__global__ __launch_bounds__(256, 2) void gemm1_silu(
    const __half* __restrict__ A, const uint32_t* __restrict__ W,
    const float* __restrict__ S, __half* __restrict__ act)
{
    __shared__ __half Alds[BM * BK];
    __shared__ __half Blds[2][BN * BK];
    const int tid  = threadIdx.x;
    const int lane = tid & 63;
    const int wid  = tid >> 6;
    const int wm = wid >> 1, wn = wid & 1;
    const int m0 = blockIdx.y * BM;
    const int c0 = blockIdx.x * BN;

    f32x4 accg[4][4], accu[4][4];
    #pragma unroll
    for (int i = 0; i < 4; ++i)
        #pragma unroll
        for (int j = 0; j < 4; ++j) {
            accg[i][j] = f32x4{0.f, 0.f, 0.f, 0.f};
            accu[i][j] = f32x4{0.f, 0.f, 0.f, 0.f};
        }

    const int c = tid & 127;
    const int rbase = (tid >> 7) * 4;

    for (int kt = 0; kt < HDIM / BK; ++kt) {
        const int k0 = kt * BK;
        #pragma unroll
        for (int i = 0; i < 4; ++i) {
            int u = tid + i * 256;
            int row = u >> 3, kb = u & 7;
            int4 v = *(const int4*)(A + (size_t)(m0 + row) * HDIM + k0 + kb * 8);
            *(int4*)((char*)Alds + row * 128 + ((kb ^ (row & 7)) << 4)) = v;
        }
        const int g = k0 >> 7;
        #pragma unroll
        for (int p = 0; p < 2; ++p) {
            const int ncol = (p ? IDIM : 0) + c0 + c;
            uint32_t s2u = scale_s2u(S[(size_t)g * (2 * IDIM) + ncol]);
            #pragma unroll
            for (int i = 0; i < 4; ++i) {
                int rl = rbase + i;
                uint32_t w = W[(size_t)(kt * 8 + rl) * (2 * IDIM) + ncol];
                int4 d = dec8(w, s2u);
                *(int4*)((char*)&Blds[p][0] + c * 128 + ((rl ^ (c & 7)) << 4)) = d;
            }
        }
        __syncthreads();
        #pragma unroll
        for (int ks = 0; ks < 2; ++ks) {
            f16x8 af[4], bg[4], bu[4];
            const int kb = ks * 4 + (lane >> 4);
            #pragma unroll
            for (int mi = 0; mi < 4; ++mi) {
                int m = wm * 64 + mi * 16 + (lane & 15);
                af[mi] = *(const f16x8*)((const char*)Alds + m * 128 + ((kb ^ (m & 7)) << 4));
            }
            #pragma unroll
            for (int ni = 0; ni < 4; ++ni) {
                int n = wn * 64 + ni * 16 + (lane & 15);
                bg[ni] = *(const f16x8*)((const char*)&Blds[0][0] + n * 128 + ((kb ^ (n & 7)) << 4));
                bu[ni] = *(const f16x8*)((const char*)&Blds[1][0] + n * 128 + ((kb ^ (n & 7)) << 4));
            }
            #pragma unroll
            for (int mi = 0; mi < 4; ++mi)
                #pragma unroll
                for (int ni = 0; ni < 4; ++ni) {
                    accg[mi][ni] = __builtin_amdgcn_mfma_f32_16x16x32_f16(af[mi], bg[ni], accg[mi][ni], 0, 0, 0);
                    accu[mi][ni] = __builtin_amdgcn_mfma_f32_16x16x32_f16(af[mi], bu[ni], accu[mi][ni], 0, 0, 0);
                }
        }
        __syncthreads();
    }
    #pragma unroll
    for (int mi = 0; mi < 4; ++mi) {
        #pragma unroll
        for (int ni = 0; ni < 4; ++ni) {
            int nlog = c0 + wn * 64 + ni * 16 + (lane & 15);
            int ncol = (nlog & ~7) | (((nlog & 3) << 1) | ((nlog >> 2) & 1));
            #pragma unroll
            for (int r = 0; r < 4; ++r) {
                int m = m0 + wm * 64 + mi * 16 + (lane >> 4) * 4 + r;
                float gv = accg[mi][ni][r];
                float uv = accu[mi][ni][r];
                float sig = 1.0f / (1.0f + __expf(-gv));
                act[(size_t)m * IDIM + ncol] = __float2half(gv * sig * uv);
            }
        }
    }
}

// ---------- GEMM2 (fused decode, r5/r8 measured ~83-90 us, no hoist) ----------
__global__ __launch_bounds__(256, 2) void gemm2_add(
    const __half* __restrict__ A, const uint32_t* __restrict__ W,
    const float* __restrict__ S, const float* __restrict__ moe,
    float* __restrict__ out)
{
    __shared__ __half Alds[BM * BK];
    __shared__ __half Blds[BN * BK];
    const int tid  = threadIdx.x;
    const int lane = tid & 63;
    const int wid  = tid >> 6;
    const int wm = wid >> 1, wn = wid & 1;
    const int m0 = blockIdx.y * BM;
    const int n0 = blockIdx.x * BN;

    f32x4 acc[4][4];
    #pragma unroll
    for (int i = 0; i < 4; ++i)
        #pragma unroll
        for (int j = 0; j < 4; ++j) acc[i][j] = f32x4{0.f, 0.f, 0.f, 0.f};

    const int c = tid & 127;
    const int rbase = (tid >> 7) * 4;

    for (int kt = 0; kt < IDIM / BK; ++kt) {
        const int k0 = kt * BK;
        #pragma unroll
        for (int i = 0; i < 4; ++i) {
            int u = tid + i * 256;
            int row = u >> 3, kb = u & 7;
            int4 v = *(const int4*)(A + (size_t)(m0 + row) * IDIM + k0 + kb * 8);
            *(int4*)((char*)Alds + row * 128 + ((kb ^ (row & 7)) << 4)) = v;
        }
        {
            const int g = k0 >> 7;
            const int ncol = n0 + c;
            uint32_t s2u = scale_s2u(S[(size_t)g * HDIM + ncol]);
            #pragma unroll
            for (int i = 0; i < 4; ++i) {
                int rl = rbase + i;
                uint32_t w = W[(size_t)(kt * 8 + rl) * HDIM + ncol];
                int4 d = dec8(w, s2u);
                *(int4*)((char*)Blds + c * 128 + ((rl ^ (c & 7)) << 4)) = d;
            }
        }
        __syncthreads();
        #pragma unroll
        for (int ks = 0; ks < 2; ++ks) {
            f16x8 af[4], bf[4];
            const int kb = ks * 4 + (lane >> 4);
            #pragma unroll
            for (int mi = 0; mi < 4; ++mi) {
                int m = wm * 64 + mi * 16 + (lane & 15);
                af[mi] = *(const f16x8*)((const char*)Alds + m * 128 + ((kb ^ (m & 7)) << 4));
            }
            #pragma unroll
            for (int ni = 0; ni < 4; ++ni) {
                int n = wn * 64 + ni * 16 + (lane & 15);
                bf[ni] = *(const f16x8*)((const char*)Blds + n * 128 + ((kb ^ (n & 7)) << 4));
            }
            #pragma unroll
            for (int mi = 0; mi < 4; ++mi)
                #pragma unroll
                for (int ni = 0; ni < 4; ++ni)
                    acc[mi][ni] = __builtin_amdgcn_mfma_f32_16x16x32_f16(af[mi], bf[ni], acc[mi][ni], 0, 0, 0);
        }
        __syncthreads();
    }
    #pragma unroll
    for (int mi = 0; mi < 4; ++mi) {
        #pragma unroll
        for (int ni = 0; ni < 4; ++ni) {
            int n = n0 + wn * 64 + ni * 16 + (lane & 15);
            #pragma unroll
            for (int r = 0; r < 4; ++r) {
                int m = m0 + wm * 64 + mi * 16 + (lane >> 4) * 4 + r;
                out[(size_t)m * HDIM + n] = moe[(size_t)m * HDIM + n] + acc[mi][ni][r];
            }
        }
    }
}

extern "C" void kernel_launch(void* const* d_in, const int* in_sizes, int n_in,
                              void* d_out, int out_size, void* d_ws, size_t ws_size,
                              hipStream_t stream) {
    const float*    hidden = (const float*)d_in[0];
    const float*    moe    = (const float*)d_in[1];
    const uint32_t* wgu    = (const uint32_t*)d_in[2];
    const float*    sgu    = (const float*)d_in[3];
    const uint32_t* wd     = (const uint32_t*)d_in[4];
    const float*    sd     = (const float*)d_in[5];
    float* out = (float*)d_out;

    const size_t sz_hidden = (size_t)TOKENS * HDIM * 2;      // 16.78 MB
    const size_t sz_act    = (size_t)TOKENS * IDIM * 2;      // 46.14 MB
    const size_t sz_wgu16  = (size_t)HDIM * 2 * IDIM * 2;    // 46.14 MB

    __half* hidden_f16 = (__half*)d_ws;
    __half* act        = (__half*)((char*)d_ws + sz_hidden);
    __half* wgu16      = (__half*)((char*)d_ws + sz_hidden + sz_act);

    const size_t need_g1 = sz_hidden + sz_act + sz_wgu16;    // 109 MB (available r5-r13)

    convert_hidden<<<dim3(TOKENS * HDIM / 8 / 256), dim3(256), 0, stream>>>(hidden, hidden_f16);

    if (ws_size >= need_g1) {
        dequant_wgu4<<<dim3(G1_NP / 256, 32), dim3(256), 0, stream>>>(wgu, sgu, wgu16);
        gemm1_s<<<dim3(G1_NP / BN, TOKENS / BM), dim3(256), 0, stream>>>(hidden_f16, wgu16, act);
    } else {
        gemm1_silu<<<dim3(IDIM / BN, TOKENS / BM), dim3(256), 0, stream>>>(hidden_f16, wgu, sgu, act);
    }

    gemm2_add<<<dim3(HDIM / BN, TOKENS / BM), dim3(256), 0, stream>>>(act, wd, sd, moe, out);
}

// Round 16
// 324.256 us; speedup vs baseline: 1.5507x; 1.0322x over previous
//
#include <hip/hip_runtime.h>
#include <hip/hip_fp16.h>
#include <stdint.h>

#define TOKENS 4096
#define HDIM   2048
#define IDIM   5632
#define BM 128
#define BN 128
#define BK 64

#define G1_NP  11264
#define G1_KSB (G1_NP * 64)    // halves per K-tile panel of Bt (gate/up)

typedef _Float16 f16x8 __attribute__((ext_vector_type(8)));
typedef float    f32x4 __attribute__((ext_vector_type(4)));

// ---------- fp4 decode helpers (verified rounds 1-15) ----------
__device__ __forceinline__ uint32_t dec2(uint32_t z, uint32_t s2u) {
    uint32_t sgn = (z << 12) & 0x80008000u;
    uint32_t h   = ((z << 9) & 0x0E000E00u) | sgn;
    __half2 hv = __builtin_bit_cast(__half2, h);
    __half2 sv = __builtin_bit_cast(__half2, s2u);
    __half2 r  = __hmul2(hv, sv);
    return __builtin_bit_cast(uint32_t, r);
}
__device__ __forceinline__ int4 dec8(uint32_t w, uint32_t s2u) {
    int4 d;
    d.x = (int)dec2( w        & 0x000F000Fu, s2u);
    d.y = (int)dec2((w >> 4)  & 0x000F000Fu, s2u);
    d.z = (int)dec2((w >> 8)  & 0x000F000Fu, s2u);
    d.w = (int)dec2((w >> 12) & 0x000F000Fu, s2u);
    return d;
}
__device__ __forceinline__ uint32_t scale_s2u(float sc) {
    uint16_t hs = __builtin_bit_cast(uint16_t, __float2half(sc * 16384.0f));
    return (uint32_t)hs * 0x00010001u;
}
__device__ __forceinline__ uint32_t packh(float lo, float hi) {
    __half2 h2 = __halves2half2(__float2half(lo), __float2half(hi));
    return __builtin_bit_cast(uint32_t, h2);
}
__device__ __forceinline__ void gl_lds16(const void* g, void* l) {
    __builtin_amdgcn_global_load_lds(
        (const __attribute__((address_space(1))) uint32_t*)g,
        (__attribute__((address_space(3))) uint32_t*)l, 16, 0, 0);
}

// ---------- hidden fp32 -> f16, sigma k-order within each 8-group ----------
__global__ __launch_bounds__(256) void convert_hidden(
    const float* __restrict__ src, __half* __restrict__ dst)
{
    int idx = blockIdx.x * 256 + threadIdx.x;   // one 8-group per thread
    const float4* s = (const float4*)src + (size_t)idx * 2;
    float4 a = s[0], b = s[1];                  // a = x0..x3, b = x4..x7
    int4 v;
    v.x = (int)packh(a.x, b.x);                 // pos 0,1 = x0,x4
    v.y = (int)packh(a.y, b.y);
    v.z = (int)packh(a.z, b.z);
    v.w = (int)packh(a.w, b.w);
    *((int4*)dst + idx) = v;
}

// ---------- dequant W_gu v5 (measured-best structure, ~38 us in r7),
// 32-col gate/up interleave -> Bt[32][11264][64], LINEAR k-word slots.
// Reads: per j-iter each wave loads two 128 B contiguous segments.
// Writes: LDS-staged (bank-spread XOR slots), then 8 x wave-contiguous
// 1 KB global bursts. Both sides instruction-coalesced. ----------
__global__ __launch_bounds__(256) void dequant_wgu5(
    const uint32_t* __restrict__ W, const float* __restrict__ S,
    __half* __restrict__ Bt)
{
    __shared__ __half L[256 * 64];   // 32 KB
    const int kt = blockIdx.y;                       // 0..31
    const int t  = threadIdx.x;
    const int np = blockIdx.x * 256 + t;             // interleaved row
    const int sc = (np >> 6) * 32 + (np & 31) + (((np >> 5) & 1) ? IDIM : 0);
    uint32_t s2u = scale_s2u(S[(size_t)(kt >> 1) * (2 * IDIM) + sc]);
    #pragma unroll
    for (int j = 0; j < 8; ++j) {
        uint32_t w = W[(size_t)(kt * 8 + j) * (2 * IDIM) + sc];
        int4 d = dec8(w, s2u);
        *(int4*)&L[t * 64 + ((j ^ (t & 7)) << 3)] = d;   // bank-spread slot
    }
    __syncthreads();
    __half* dst = Bt + (size_t)kt * G1_KSB + (size_t)blockIdx.x * 256 * 64;
    #pragma unroll
    for (int k = 0; k < 8; ++k) {
        int c = k * 256 + t;                 // chunk: row=c>>3, word s=c&7
        int row = c >> 3, s = c & 7;
        int4 d = *(const int4*)&L[row * 64 + ((s ^ (row & 7)) << 3)];
        *(int4*)(dst + c * 8) = d;           // lane-contiguous 1 KB per instr
    }
}

// ---------- GEMM1: r11's measured kernel (176 us, 53% MfmaUtil, 0 conflicts).
// 128x128 tile, 256 thr, 4 waves (64x64), single-buffer 32 KB LDS, gl_lds
// staging with per-lane source swizzle, hoisted LDS-read offsets.
// Epilogue: 32-col gate/up interleave (ni=0,1 gate / ni=2,3 up). ----------
__global__ __launch_bounds__(256, 4) void gemm1_s(
    const __half* __restrict__ A, const __half* __restrict__ Bt,
    __half* __restrict__ act)
{
    __shared__ __half Alds[BM * 64];   // 16 KB
    __shared__ __half Blds[BN * 64];   // 16 KB
    const int tid  = threadIdx.x;
    const int lane = tid & 63;
    const int wid  = tid >> 6;
    const int wm = wid >> 1, wn = wid & 1;
    const int m0 = blockIdx.y * BM;
    const int n0 = blockIdx.x * BN;

    f32x4 acc[4][4];
    #pragma unroll
    for (int i = 0; i < 4; ++i)
        #pragma unroll
        for (int j = 0; j < 4; ++j) acc[i][j] = f32x4{0.f, 0.f, 0.f, 0.f};

    const __half* srcA[4];
    const __half* srcB[4];
    #pragma unroll
    for (int i = 0; i < 4; ++i) {
        int u = i * 256 + tid, row = u >> 3, s = u & 7, sl = s ^ (row & 7);
        srcA[i] = A  + (size_t)(m0 + row) * HDIM + sl * 8;
        srcB[i] = Bt + (size_t)(n0 + row) * 64 + sl * 8;
    }

    // hoisted LDS-read byte offsets (invariant across kt)
    int aoff[4][2], boff[4][2];
    #pragma unroll
    for (int f = 0; f < 4; ++f)
        #pragma unroll
        for (int ks = 0; ks < 2; ++ks) {
            int kb = ks * 4 + (lane >> 4);
            int ra = wm * 64 + f * 16 + (lane & 15);
            int rb = wn * 64 + f * 16 + (lane & 15);
            aoff[f][ks] = ra * 128 + ((kb ^ (ra & 7)) << 4);
            boff[f][ks] = rb * 128 + ((kb ^ (rb & 7)) << 4);
        }

    for (int kt = 0; kt < HDIM / 64; ++kt) {
        #pragma unroll
        for (int i = 0; i < 4; ++i) {
            int u = i * 256 + tid;
            gl_lds16(srcA[i], (char*)Alds + u * 16);
            gl_lds16(srcB[i], (char*)Blds + u * 16);
            srcA[i] += 64;
            srcB[i] += G1_KSB;
        }
        __syncthreads();
        #pragma unroll
        for (int ks = 0; ks < 2; ++ks) {
            f16x8 af[4], bf[4];
            #pragma unroll
            for (int f = 0; f < 4; ++f) {
                af[f] = *(const f16x8*)((const char*)Alds + aoff[f][ks]);
                bf[f] = *(const f16x8*)((const char*)Blds + boff[f][ks]);
            }
            #pragma unroll
            for (int mi = 0; mi < 4; ++mi)
                #pragma unroll
                for (int ni = 0; ni < 4; ++ni)
                    acc[mi][ni] = __builtin_amdgcn_mfma_f32_16x16x32_f16(af[mi], bf[ni], acc[mi][ni], 0, 0, 0);
        }
        __syncthreads();
    }

    // epilogue: 32-col interleave -> ni=0,1 gate cols, ni=2,3 up cols. sigma slot.
    const int pairbase = ((n0 + wn * 64) >> 6) * 32;
    #pragma unroll
    for (int mi = 0; mi < 4; ++mi) {
        #pragma unroll
        for (int q = 0; q < 2; ++q) {
            int gcol = pairbase + q * 16 + (lane & 15);
            int colstore = (gcol & ~7) | (((gcol & 3) << 1) | ((gcol >> 2) & 1));
            #pragma unroll
            for (int r = 0; r < 4; ++r) {
                int m = m0 + wm * 64 + mi * 16 + (lane >> 4) * 4 + r;
                float gv = acc[mi][q][r];
                float uv = acc[mi][q + 2][r];
                float sig = 1.0f / (1.0f + __expf(-gv));
                act[(size_t)m * IDIM + colstore] = __float2half(gv * sig * uv);
            }
        }
    }
}

// ---------- round-1 fused-decode GEMM1 (fallback if ws too small) ----------
__global__ __launch_bounds__(256, 2) void gemm1_silu(
    const __half* __restrict__ A, const uint32_t* __restrict__ W,
    const float* __restrict__ S, __half* __restrict__ act)
{
    __shared__ __half Alds[BM * BK];
    __shared__ __half Blds[2][BN * BK];
    const int tid  = threadIdx.x;
    const int lane = tid & 63;
    const int wid  = tid >> 6;
    const int wm = wid >> 1, wn = wid & 1;
    const int m0 = blockIdx.y * BM;
    const int c0 = blockIdx.x * BN;

    f32x4 accg[4][4], accu[4][4];
    #pragma unroll
    for (int i = 0; i < 4; ++i)
        #pragma unroll
        for (int j = 0; j < 4; ++j) {
            accg[i][j] = f32x4{0.f, 0.f, 0.f, 0.f};
            accu[i][j] = f32x4{0.f, 0.f, 0.f, 0.f};
        }

    const int c = tid & 127;
    const int rbase = (tid >> 7) * 4;

    for (int kt = 0; kt < HDIM / BK; ++kt) {
        const int k0 = kt * BK;
        #pragma unroll
        for (int i = 0; i < 4; ++i) {
            int u = tid + i * 256;
            int row = u >> 3, kb = u & 7;
            int4 v = *(const int4*)(A + (size_t)(m0 + row) * HDIM + k0 + kb * 8);
            *(int4*)((char*)Alds + row * 128 + ((kb ^ (row & 7)) << 4)) = v;
        }
        const int g = k0 >> 7;
        #pragma unroll
        for (int p = 0; p < 2; ++p) {
            const int ncol = (p ? IDIM : 0) + c0 + c;
            uint32_t s2u = scale_s2u(S[(size_t)g * (2 * IDIM) + ncol]);
            #pragma unroll
            for (int i = 0; i < 4; ++i) {
                int rl = rbase + i;
                uint32_t w = W[(size_t)(kt * 8 + rl) * (2 * IDIM) + ncol];
                int4 d = dec8(w, s2u);
                *(int4*)((char*)&Blds[p][0] + c * 128 + ((rl ^ (c & 7)) << 4)) = d;
            }
        }
        __syncthreads();
        #pragma unroll
        for (int ks = 0; ks < 2; ++ks) {
            f16x8 af[4], bg[4], bu[4];
            const int kb = ks * 4 + (lane >> 4);
            #pragma unroll
            for (int mi = 0; mi < 4; ++mi) {
                int m = wm * 64 + mi * 16 + (lane & 15);
                af[mi] = *(const f16x8*)((const char*)Alds + m * 128 + ((kb ^ (m & 7)) << 4));
            }
            #pragma unroll
            for (int ni = 0; ni < 4; ++ni) {
                int n = wn * 64 + ni * 16 + (lane & 15);
                bg[ni] = *(const f16x8*)((const char*)&Blds[0][0] + n * 128 + ((kb ^ (n & 7)) << 4));
                bu[ni] = *(const f16x8*)((const char*)&Blds[1][0] + n * 128 + ((kb ^ (n & 7)) << 4));
            }
            #pragma unroll
            for (int mi = 0; mi < 4; ++mi)
                #pragma unroll
                for (int ni = 0; ni < 4; ++ni) {
                    accg[mi][ni] = __builtin_amdgcn_mfma_f32_16x16x32_f16(af[mi], bg[ni], accg[mi][ni], 0, 0, 0);
                    accu[mi][ni] = __builtin_amdgcn_mfma_f32_16x16x32_f16(af[mi], bu[ni], accu[mi][ni], 0, 0, 0);
                }
        }
        __syncthreads();
    }
    #pragma unroll
    for (int mi = 0; mi < 4; ++mi) {
        #pragma unroll
        for (int ni = 0; ni < 4; ++ni) {
            int nlog = c0 + wn * 64 + ni * 16 + (lane & 15);
            int ncol = (nlog & ~7) | (((nlog & 3) << 1) | ((nlog >> 2) & 1));
            #pragma unroll
            for (int r = 0; r < 4; ++r) {
                int m = m0 + wm * 64 + mi * 16 + (lane >> 4) * 4 + r;
                float gv = accg[mi][ni][r];
                float uv = accu[mi][ni][r];
                float sig = 1.0f / (1.0f + __expf(-gv));
                act[(size_t)m * IDIM + ncol] = __float2half(gv * sig * uv);
            }
        }
    }
}

// ---------- GEMM2 (fused decode, r11 hoisted variant): out = moe + act@deq(Wd) ----------
__global__ __launch_bounds__(256, 2) void gemm2_add(
    const __half* __restrict__ A, const uint32_t* __restrict__ W,
    const float* __restrict__ S, const float* __restrict__ moe,
    float* __restrict__ out)
{
    __shared__ __half Alds[BM * BK];
    __shared__ __half Blds[BN * BK];
    const int tid  = threadIdx.x;
    const int lane = tid & 63;
    const int wid  = tid >> 6;
    const int wm = wid >> 1, wn = wid & 1;
    const int m0 = blockIdx.y * BM;
    const int n0 = blockIdx.x * BN;

    f32x4 acc[4][4];
    #pragma unroll
    for (int i = 0; i < 4; ++i)
        #pragma unroll
        for (int j = 0; j < 4; ++j) acc[i][j] = f32x4{0.f, 0.f, 0.f, 0.f};

    const int c = tid & 127;
    const int rbase = (tid >> 7) * 4;

    int aoff[4][2], boff[4][2];
    #pragma unroll
    for (int f = 0; f < 4; ++f)
        #pragma unroll
        for (int ks = 0; ks < 2; ++ks) {
            int kb = ks * 4 + (lane >> 4);
            int ra = wm * 64 + f * 16 + (lane & 15);
            int rb = wn * 64 + f * 16 + (lane & 15);
            aoff[f][ks] = ra * 128 + ((kb ^ (ra & 7)) << 4);
            boff[f][ks] = rb * 128 + ((kb ^ (rb & 7)) << 4);
        }

    for (int kt = 0; kt < IDIM / BK; ++kt) {
        const int k0 = kt * BK;
        #pragma unroll
        for (int i = 0; i < 4; ++i) {
            int u = tid + i * 256;
            int row = u >> 3, kb = u & 7;
            int4 v = *(const int4*)(A + (size_t)(m0 + row) * IDIM + k0 + kb * 8);
            *(int4*)((char*)Alds + row * 128 + ((kb ^ (row & 7)) << 4)) = v;
        }
        {
            const int g = k0 >> 7;
            const int ncol = n0 + c;
            uint32_t s2u = scale_s2u(S[(size_t)g * HDIM + ncol]);
            #pragma unroll
            for (int i = 0; i < 4; ++i) {
                int rl = rbase + i;
                uint32_t w = W[(size_t)(kt * 8 + rl) * HDIM + ncol];
                int4 d = dec8(w, s2u);
                *(int4*)((char*)Blds + c * 128 + ((rl ^ (c & 7)) << 4)) = d;
            }
        }
        __syncthreads();
        #pragma unroll
        for (int ks = 0; ks < 2; ++ks) {
            f16x8 af[4], bf[4];
            #pragma unroll
            for (int f = 0; f < 4; ++f) {
                af[f] = *(const f16x8*)((const char*)Alds + aoff[f][ks]);
                bf[f] = *(const f16x8*)((const char*)Blds + boff[f][ks]);
            }
            #pragma unroll
            for (int mi = 0; mi < 4; ++mi)
                #pragma unroll
                for (int ni = 0; ni < 4; ++ni)
                    acc[mi][ni] = __builtin_amdgcn_mfma_f32_16x16x32_f16(af[mi], bf[ni], acc[mi][ni], 0, 0, 0);
        }
        __syncthreads();
    }
    #pragma unroll
    for (int mi = 0; mi < 4; ++mi) {
        #pragma unroll
        for (int ni = 0; ni < 4; ++ni) {
            int n = n0 + wn * 64 + ni * 16 + (lane & 15);
            #pragma unroll
            for (int r = 0; r < 4; ++r) {
                int m = m0 + wm * 64 + mi * 16 + (lane >> 4) * 4 + r;
                out[(size_t)m * HDIM + n] = moe[(size_t)m * HDIM + n] + acc[mi][ni][r];
            }
        }
    }
}

extern "C" void kernel_launch(void* const* d_in, const int* in_sizes, int n_in,
                              void* d_out, int out_size, void* d_ws, size_t ws_size,
                              hipStream_t stream) {
    const float*    hidden = (const float*)d_in[0];
    const float*    moe    = (const float*)d_in[1];
    const uint32_t* wgu    = (const uint32_t*)d_in[2];
    const float*    sgu    = (const float*)d_in[3];
    const uint32_t* wd     = (const uint32_t*)d_in[4];
    const float*    sd     = (const float*)d_in[5];
    float* out = (float*)d_out;

    const size_t sz_hidden = (size_t)TOKENS * HDIM * 2;      // 16.78 MB
    const size_t sz_act    = (size_t)TOKENS * IDIM * 2;      // 46.14 MB
    const size_t sz_wgu16  = (size_t)HDIM * 2 * IDIM * 2;    // 46.14 MB

    __half* hidden_f16 = (__half*)d_ws;
    __half* act        = (__half*)((char*)d_ws + sz_hidden);
    __half* wgu16      = (__half*)((char*)d_ws + sz_hidden + sz_act);

    const size_t need_g1 = sz_hidden + sz_act + sz_wgu16;    // 109 MB (available r5-r15)

    convert_hidden<<<dim3(TOKENS * HDIM / 8 / 256), dim3(256), 0, stream>>>(hidden, hidden_f16);

    if (ws_size >= need_g1) {
        dequant_wgu5<<<dim3(G1_NP / 256, 32), dim3(256), 0, stream>>>(wgu, sgu, wgu16);
        gemm1_s<<<dim3(G1_NP / BN, TOKENS / BM), dim3(256), 0, stream>>>(hidden_f16, wgu16, act);
    } else {
        gemm1_silu<<<dim3(IDIM / BN, TOKENS / BM), dim3(256), 0, stream>>>(hidden_f16, wgu, sgu, act);
    }

    gemm2_add<<<dim3(HDIM / BN, TOKENS / BM), dim3(256), 0, stream>>>(act, wd, sd, moe, out);
}

// Round 17
// 317.694 us; speedup vs baseline: 1.5827x; 1.0207x over previous
//
#include <hip/hip_runtime.h>
#include <hip/hip_fp16.h>
#include <stdint.h>

#define TOKENS 4096
#define HDIM   2048
#define IDIM   5632
#define BM 128
#define BN 128
#define BK 64

#define G1_NP  11264
#define G1_KSB (G1_NP * 64)    // halves per K-tile panel of Bt (gate/up)
#define G2_KSB (HDIM * 64)     // halves per K-tile panel of Btd (down)

typedef _Float16 f16x8 __attribute__((ext_vector_type(8)));
typedef float    f32x4 __attribute__((ext_vector_type(4)));

// ---------- fp4 decode helpers (verified rounds 1-16) ----------
__device__ __forceinline__ uint32_t dec2(uint32_t z, uint32_t s2u) {
    uint32_t sgn = (z << 12) & 0x80008000u;
    uint32_t h   = ((z << 9) & 0x0E000E00u) | sgn;
    __half2 hv = __builtin_bit_cast(__half2, h);
    __half2 sv = __builtin_bit_cast(__half2, s2u);
    __half2 r  = __hmul2(hv, sv);
    return __builtin_bit_cast(uint32_t, r);
}
__device__ __forceinline__ int4 dec8(uint32_t w, uint32_t s2u) {
    int4 d;
    d.x = (int)dec2( w        & 0x000F000Fu, s2u);
    d.y = (int)dec2((w >> 4)  & 0x000F000Fu, s2u);
    d.z = (int)dec2((w >> 8)  & 0x000F000Fu, s2u);
    d.w = (int)dec2((w >> 12) & 0x000F000Fu, s2u);
    return d;
}
__device__ __forceinline__ uint32_t scale_s2u(float sc) {
    uint16_t hs = __builtin_bit_cast(uint16_t, __float2half(sc * 16384.0f));
    return (uint32_t)hs * 0x00010001u;
}
__device__ __forceinline__ uint32_t packh(float lo, float hi) {
    __half2 h2 = __halves2half2(__float2half(lo), __float2half(hi));
    return __builtin_bit_cast(uint32_t, h2);
}
__device__ __forceinline__ void gl_lds16(const void* g, void* l) {
    __builtin_amdgcn_global_load_lds(
        (const __attribute__((address_space(1))) uint32_t*)g,
        (__attribute__((address_space(3))) uint32_t*)l, 16, 0, 0);
}

// ---------- hidden fp32 -> f16, sigma k-order within each 8-group ----------
__global__ __launch_bounds__(256) void convert_hidden(
    const float* __restrict__ src, __half* __restrict__ dst)
{
    int idx = blockIdx.x * 256 + threadIdx.x;   // one 8-group per thread
    const float4* s = (const float4*)src + (size_t)idx * 2;
    float4 a = s[0], b = s[1];                  // a = x0..x3, b = x4..x7
    int4 v;
    v.x = (int)packh(a.x, b.x);                 // pos 0,1 = x0,x4
    v.y = (int)packh(a.y, b.y);
    v.z = (int)packh(a.z, b.z);
    v.w = (int)packh(a.w, b.w);
    *((int4*)dst + idx) = v;
}

// ---------- dequant W_gu v5 (r16 control): 32-col gate/up interleave ->
// Bt[32][11264][64], linear k-word slots; LDS-staged, both sides coalesced. ----------
__global__ __launch_bounds__(256) void dequant_wgu5(
    const uint32_t* __restrict__ W, const float* __restrict__ S,
    __half* __restrict__ Bt)
{
    __shared__ __half L[256 * 64];   // 32 KB
    const int kt = blockIdx.y;                       // 0..31
    const int t  = threadIdx.x;
    const int np = blockIdx.x * 256 + t;             // interleaved row
    const int sc = (np >> 6) * 32 + (np & 31) + (((np >> 5) & 1) ? IDIM : 0);
    uint32_t s2u = scale_s2u(S[(size_t)(kt >> 1) * (2 * IDIM) + sc]);
    #pragma unroll
    for (int j = 0; j < 8; ++j) {
        uint32_t w = W[(size_t)(kt * 8 + j) * (2 * IDIM) + sc];
        int4 d = dec8(w, s2u);
        *(int4*)&L[t * 64 + ((j ^ (t & 7)) << 3)] = d;   // bank-spread slot
    }
    __syncthreads();
    __half* dst = Bt + (size_t)kt * G1_KSB + (size_t)blockIdx.x * 256 * 64;
    #pragma unroll
    for (int k = 0; k < 8; ++k) {
        int c = k * 256 + t;                 // chunk: row=c>>3, word s=c&7
        int row = c >> 3, s = c & 7;
        int4 d = *(const int4*)&L[row * 64 + ((s ^ (row & 7)) << 3)];
        *(int4*)(dst + c * 8) = d;           // lane-contiguous 1 KB per instr
    }
}

// ---------- dequant W_d v5: Btd[88][2048][64], same LDS-staged structure ----------
__global__ __launch_bounds__(256) void dequant_wd5(
    const uint32_t* __restrict__ W, const float* __restrict__ S,
    __half* __restrict__ Bt)
{
    __shared__ __half L[256 * 64];   // 32 KB
    const int kt = blockIdx.y;                       // 0..87
    const int t  = threadIdx.x;
    const int n  = blockIdx.x * 256 + t;             // output col 0..2047
    uint32_t s2u = scale_s2u(S[(size_t)(kt >> 1) * HDIM + n]);
    #pragma unroll
    for (int j = 0; j < 8; ++j) {
        uint32_t w = W[(size_t)(kt * 8 + j) * HDIM + n];
        int4 d = dec8(w, s2u);
        *(int4*)&L[t * 64 + ((j ^ (t & 7)) << 3)] = d;
    }
    __syncthreads();
    __half* dst = Bt + (size_t)kt * G2_KSB + (size_t)blockIdx.x * 256 * 64;
    #pragma unroll
    for (int k = 0; k < 8; ++k) {
        int c = k * 256 + t;
        int row = c >> 3, s = c & 7;
        int4 d = *(const int4*)&L[row * 64 + ((s ^ (row & 7)) << 3)];
        *(int4*)(dst + c * 8) = d;
    }
}

// ---------- GEMM1: r11/r16 measured kernel (176 us, 53% MfmaUtil, 0 conflicts) ----------
__global__ __launch_bounds__(256, 4) void gemm1_s(
    const __half* __restrict__ A, const __half* __restrict__ Bt,
    __half* __restrict__ act)
{
    __shared__ __half Alds[BM * 64];   // 16 KB
    __shared__ __half Blds[BN * 64];   // 16 KB
    const int tid  = threadIdx.x;
    const int lane = tid & 63;
    const int wid  = tid >> 6;
    const int wm = wid >> 1, wn = wid & 1;
    const int m0 = blockIdx.y * BM;
    const int n0 = blockIdx.x * BN;

    f32x4 acc[4][4];
    #pragma unroll
    for (int i = 0; i < 4; ++i)
        #pragma unroll
        for (int j = 0; j < 4; ++j) acc[i][j] = f32x4{0.f, 0.f, 0.f, 0.f};

    const __half* srcA[4];
    const __half* srcB[4];
    #pragma unroll
    for (int i = 0; i < 4; ++i) {
        int u = i * 256 + tid, row = u >> 3, s = u & 7, sl = s ^ (row & 7);
        srcA[i] = A  + (size_t)(m0 + row) * HDIM + sl * 8;
        srcB[i] = Bt + (size_t)(n0 + row) * 64 + sl * 8;
    }

    int aoff[4][2], boff[4][2];
    #pragma unroll
    for (int f = 0; f < 4; ++f)
        #pragma unroll
        for (int ks = 0; ks < 2; ++ks) {
            int kb = ks * 4 + (lane >> 4);
            int ra = wm * 64 + f * 16 + (lane & 15);
            int rb = wn * 64 + f * 16 + (lane & 15);
            aoff[f][ks] = ra * 128 + ((kb ^ (ra & 7)) << 4);
            boff[f][ks] = rb * 128 + ((kb ^ (rb & 7)) << 4);
        }

    for (int kt = 0; kt < HDIM / 64; ++kt) {
        #pragma unroll
        for (int i = 0; i < 4; ++i) {
            int u = i * 256 + tid;
            gl_lds16(srcA[i], (char*)Alds + u * 16);
            gl_lds16(srcB[i], (char*)Blds + u * 16);
            srcA[i] += 64;
            srcB[i] += G1_KSB;
        }
        __syncthreads();
        #pragma unroll
        for (int ks = 0; ks < 2; ++ks) {
            f16x8 af[4], bf[4];
            #pragma unroll
            for (int f = 0; f < 4; ++f) {
                af[f] = *(const f16x8*)((const char*)Alds + aoff[f][ks]);
                bf[f] = *(const f16x8*)((const char*)Blds + boff[f][ks]);
            }
            #pragma unroll
            for (int mi = 0; mi < 4; ++mi)
                #pragma unroll
                for (int ni = 0; ni < 4; ++ni)
                    acc[mi][ni] = __builtin_amdgcn_mfma_f32_16x16x32_f16(af[mi], bf[ni], acc[mi][ni], 0, 0, 0);
        }
        __syncthreads();
    }

    // epilogue: 32-col interleave -> ni=0,1 gate cols, ni=2,3 up cols. sigma slot.
    const int pairbase = ((n0 + wn * 64) >> 6) * 32;
    #pragma unroll
    for (int mi = 0; mi < 4; ++mi) {
        #pragma unroll
        for (int q = 0; q < 2; ++q) {
            int gcol = pairbase + q * 16 + (lane & 15);
            int colstore = (gcol & ~7) | (((gcol & 3) << 1) | ((gcol >> 2) & 1));
            #pragma unroll
            for (int r = 0; r < 4; ++r) {
                int m = m0 + wm * 64 + mi * 16 + (lane >> 4) * 4 + r;
                float gv = acc[mi][q][r];
                float uv = acc[mi][q + 2][r];
                float sig = 1.0f / (1.0f + __expf(-gv));
                act[(size_t)m * IDIM + colstore] = __float2half(gv * sig * uv);
            }
        }
    }
}

// ---------- GEMM2 pre-dequant (r6 verified, budget-proven ~70 us):
// gemm1_s twin, zero in-loop decode, moe-add epilogue ----------
__global__ __launch_bounds__(256, 4) void gemm2_s(
    const __half* __restrict__ A, const __half* __restrict__ Bt,
    const float* __restrict__ moe, float* __restrict__ out)
{
    __shared__ __half Alds[BM * 64];   // 16 KB
    __shared__ __half Blds[BN * 64];   // 16 KB
    const int tid  = threadIdx.x;
    const int lane = tid & 63;
    const int wid  = tid >> 6;
    const int wm = wid >> 1, wn = wid & 1;
    const int m0 = blockIdx.y * BM;
    const int n0 = blockIdx.x * BN;

    f32x4 acc[4][4];
    #pragma unroll
    for (int i = 0; i < 4; ++i)
        #pragma unroll
        for (int j = 0; j < 4; ++j) acc[i][j] = f32x4{0.f, 0.f, 0.f, 0.f};

    const __half* srcA[4];
    const __half* srcB[4];
    #pragma unroll
    for (int i = 0; i < 4; ++i) {
        int u = i * 256 + tid, row = u >> 3, s = u & 7, sl = s ^ (row & 7);
        srcA[i] = A  + (size_t)(m0 + row) * IDIM + sl * 8;
        srcB[i] = Bt + (size_t)(n0 + row) * 64 + sl * 8;
    }

    int aoff[4][2], boff[4][2];
    #pragma unroll
    for (int f = 0; f < 4; ++f)
        #pragma unroll
        for (int ks = 0; ks < 2; ++ks) {
            int kb = ks * 4 + (lane >> 4);
            int ra = wm * 64 + f * 16 + (lane & 15);
            int rb = wn * 64 + f * 16 + (lane & 15);
            aoff[f][ks] = ra * 128 + ((kb ^ (ra & 7)) << 4);
            boff[f][ks] = rb * 128 + ((kb ^ (rb & 7)) << 4);
        }

    for (int kt = 0; kt < IDIM / 64; ++kt) {
        #pragma unroll
        for (int i = 0; i < 4; ++i) {
            int u = i * 256 + tid;
            gl_lds16(srcA[i], (char*)Alds + u * 16);
            gl_lds16(srcB[i], (char*)Blds + u * 16);
            srcA[i] += 64;
            srcB[i] += G2_KSB;
        }
        __syncthreads();
        #pragma unroll
        for (int ks = 0; ks < 2; ++ks) {
            f16x8 af[4], bf[4];
            #pragma unroll
            for (int f = 0; f < 4; ++f) {
                af[f] = *(const f16x8*)((const char*)Alds + aoff[f][ks]);
                bf[f] = *(const f16x8*)((const char*)Blds + boff[f][ks]);
            }
            #pragma unroll
            for (int mi = 0; mi < 4; ++mi)
                #pragma unroll
                for (int ni = 0; ni < 4; ++ni)
                    acc[mi][ni] = __builtin_amdgcn_mfma_f32_16x16x32_f16(af[mi], bf[ni], acc[mi][ni], 0, 0, 0);
        }
        __syncthreads();
    }
    #pragma unroll
    for (int mi = 0; mi < 4; ++mi) {
        #pragma unroll
        for (int ni = 0; ni < 4; ++ni) {
            int n = n0 + wn * 64 + ni * 16 + (lane & 15);
            #pragma unroll
            for (int r = 0; r < 4; ++r) {
                int m = m0 + wm * 64 + mi * 16 + (lane >> 4) * 4 + r;
                out[(size_t)m * HDIM + n] = moe[(size_t)m * HDIM + n] + acc[mi][ni][r];
            }
        }
    }
}

// ---------- round-1 fused-decode GEMM1 (fallback if ws too small) ----------
__global__ __launch_bounds__(256, 2) void gemm1_silu(
    const __half* __restrict__ A, const uint32_t* __restrict__ W,
    const float* __restrict__ S, __half* __restrict__ act)
{
    __shared__ __half Alds[BM * BK];
    __shared__ __half Blds[2][BN * BK];
    const int tid  = threadIdx.x;
    const int lane = tid & 63;
    const int wid  = tid >> 6;
    const int wm = wid >> 1, wn = wid & 1;
    const int m0 = blockIdx.y * BM;
    const int c0 = blockIdx.x * BN;

    f32x4 accg[4][4], accu[4][4];
    #pragma unroll
    for (int i = 0; i < 4; ++i)
        #pragma unroll
        for (int j = 0; j < 4; ++j) {
            accg[i][j] = f32x4{0.f, 0.f, 0.f, 0.f};
            accu[i][j] = f32x4{0.f, 0.f, 0.f, 0.f};
        }

    const int c = tid & 127;
    const int rbase = (tid >> 7) * 4;

    for (int kt = 0; kt < HDIM / BK; ++kt) {
        const int k0 = kt * BK;
        #pragma unroll
        for (int i = 0; i < 4; ++i) {
            int u = tid + i * 256;
            int row = u >> 3, kb = u & 7;
            int4 v = *(const int4*)(A + (size_t)(m0 + row) * HDIM + k0 + kb * 8);
            *(int4*)((char*)Alds + row * 128 + ((kb ^ (row & 7)) << 4)) = v;
        }
        const int g = k0 >> 7;
        #pragma unroll
        for (int p = 0; p < 2; ++p) {
            const int ncol = (p ? IDIM : 0) + c0 + c;
            uint32_t s2u = scale_s2u(S[(size_t)g * (2 * IDIM) + ncol]);
            #pragma unroll
            for (int i = 0; i < 4; ++i) {
                int rl = rbase + i;
                uint32_t w = W[(size_t)(kt * 8 + rl) * (2 * IDIM) + ncol];
                int4 d = dec8(w, s2u);
                *(int4*)((char*)&Blds[p][0] + c * 128 + ((rl ^ (c & 7)) << 4)) = d;
            }
        }
        __syncthreads();
        #pragma unroll
        for (int ks = 0; ks < 2; ++ks) {
            f16x8 af[4], bg[4], bu[4];
            const int kb = ks * 4 + (lane >> 4);
            #pragma unroll
            for (int mi = 0; mi < 4; ++mi) {
                int m = wm * 64 + mi * 16 + (lane & 15);
                af[mi] = *(const f16x8*)((const char*)Alds + m * 128 + ((kb ^ (m & 7)) << 4));
            }
            #pragma unroll
            for (int ni = 0; ni < 4; ++ni) {
                int n = wn * 64 + ni * 16 + (lane & 15);
                bg[ni] = *(const f16x8*)((const char*)&Blds[0][0] + n * 128 + ((kb ^ (n & 7)) << 4));
                bu[ni] = *(const f16x8*)((const char*)&Blds[1][0] + n * 128 + ((kb ^ (n & 7)) << 4));
            }
            #pragma unroll
            for (int mi = 0; mi < 4; ++mi)
                #pragma unroll
                for (int ni = 0; ni < 4; ++ni) {
                    accg[mi][ni] = __builtin_amdgcn_mfma_f32_16x16x32_f16(af[mi], bg[ni], accg[mi][ni], 0, 0, 0);
                    accu[mi][ni] = __builtin_amdgcn_mfma_f32_16x16x32_f16(af[mi], bu[ni], accu[mi][ni], 0, 0, 0);
                }
        }
        __syncthreads();
    }
    #pragma unroll
    for (int mi = 0; mi < 4; ++mi) {
        #pragma unroll
        for (int ni = 0; ni < 4; ++ni) {
            int nlog = c0 + wn * 64 + ni * 16 + (lane & 15);
            int ncol = (nlog & ~7) | (((nlog & 3) << 1) | ((nlog >> 2) & 1));
            #pragma unroll
            for (int r = 0; r < 4; ++r) {
                int m = m0 + wm * 64 + mi * 16 + (lane >> 4) * 4 + r;
                float gv = accg[mi][ni][r];
                float uv = accu[mi][ni][r];
                float sig = 1.0f / (1.0f + __expf(-gv));
                act[(size_t)m * IDIM + ncol] = __float2half(gv * sig * uv);
            }
        }
    }
}

// ---------- GEMM2 fused-decode fallback (r16) ----------
__global__ __launch_bounds__(256, 2) void gemm2_add(
    const __half* __restrict__ A, const uint32_t* __restrict__ W,
    const float* __restrict__ S, const float* __restrict__ moe,
    float* __restrict__ out)
{
    __shared__ __half Alds[BM * BK];
    __shared__ __half Blds[BN * BK];
    const int tid  = threadIdx.x;
    const int lane = tid & 63;
    const int wid  = tid >> 6;
    const int wm = wid >> 1, wn = wid & 1;
    const int m0 = blockIdx.y * BM;
    const int n0 = blockIdx.x * BN;

    f32x4 acc[4][4];
    #pragma unroll
    for (int i = 0; i < 4; ++i)
        #pragma unroll
        for (int j = 0; j < 4; ++j) acc[i][j] = f32x4{0.f, 0.f, 0.f, 0.f};

    const int c = tid & 127;
    const int rbase = (tid >> 7) * 4;

    int aoff[4][2], boff[4][2];
    #pragma unroll
    for (int f = 0; f < 4; ++f)
        #pragma unroll
        for (int ks = 0; ks < 2; ++ks) {
            int kb = ks * 4 + (lane >> 4);
            int ra = wm * 64 + f * 16 + (lane & 15);
            int rb = wn * 64 + f * 16 + (lane & 15);
            aoff[f][ks] = ra * 128 + ((kb ^ (ra & 7)) << 4);
            boff[f][ks] = rb * 128 + ((kb ^ (rb & 7)) << 4);
        }

    for (int kt = 0; kt < IDIM / BK; ++kt) {
        const int k0 = kt * BK;
        #pragma unroll
        for (int i = 0; i < 4; ++i) {
            int u = tid + i * 256;
            int row = u >> 3, kb = u & 7;
            int4 v = *(const int4*)(A + (size_t)(m0 + row) * IDIM + k0 + kb * 8);
            *(int4*)((char*)Alds + row * 128 + ((kb ^ (row & 7)) << 4)) = v;
        }
        {
            const int g = k0 >> 7;
            const int ncol = n0 + c;
            uint32_t s2u = scale_s2u(S[(size_t)g * HDIM + ncol]);
            #pragma unroll
            for (int i = 0; i < 4; ++i) {
                int rl = rbase + i;
                uint32_t w = W[(size_t)(kt * 8 + rl) * HDIM + ncol];
                int4 d = dec8(w, s2u);
                *(int4*)((char*)Blds + c * 128 + ((rl ^ (c & 7)) << 4)) = d;
            }
        }
        __syncthreads();
        #pragma unroll
        for (int ks = 0; ks < 2; ++ks) {
            f16x8 af[4], bf[4];
            #pragma unroll
            for (int f = 0; f < 4; ++f) {
                af[f] = *(const f16x8*)((const char*)Alds + aoff[f][ks]);
                bf[f] = *(const f16x8*)((const char*)Blds + boff[f][ks]);
            }
            #pragma unroll
            for (int mi = 0; mi < 4; ++mi)
                #pragma unroll
                for (int ni = 0; ni < 4; ++ni)
                    acc[mi][ni] = __builtin_amdgcn_mfma_f32_16x16x32_f16(af[mi], bf[ni], acc[mi][ni], 0, 0, 0);
        }
        __syncthreads();
    }
    #pragma unroll
    for (int mi = 0; mi < 4; ++mi) {
        #pragma unroll
        for (int ni = 0; ni < 4; ++ni) {
            int n = n0 + wn * 64 + ni * 16 + (lane & 15);
            #pragma unroll
            for (int r = 0; r < 4; ++r) {
                int m = m0 + wm * 64 + mi * 16 + (lane >> 4) * 4 + r;
                out[(size_t)m * HDIM + n] = moe[(size_t)m * HDIM + n] + acc[mi][ni][r];
            }
        }
    }
}

extern "C" void kernel_launch(void* const* d_in, const int* in_sizes, int n_in,
                              void* d_out, int out_size, void* d_ws, size_t ws_size,
                              hipStream_t stream) {
    const float*    hidden = (const float*)d_in[0];
    const float*    moe    = (const float*)d_in[1];
    const uint32_t* wgu    = (const uint32_t*)d_in[2];
    const float*    sgu    = (const float*)d_in[3];
    const uint32_t* wd     = (const uint32_t*)d_in[4];
    const float*    sd     = (const float*)d_in[5];
    float* out = (float*)d_out;

    const size_t sz_hidden = (size_t)TOKENS * HDIM * 2;      // 16.78 MB
    const size_t sz_act    = (size_t)TOKENS * IDIM * 2;      // 46.14 MB
    const size_t sz_wgu16  = (size_t)HDIM * 2 * IDIM * 2;    // 46.14 MB
    const size_t sz_wd16   = (size_t)IDIM * HDIM * 2;        // 23.07 MB

    __half* hidden_f16 = (__half*)d_ws;
    __half* act        = (__half*)((char*)d_ws + sz_hidden);
    __half* wgu16      = (__half*)((char*)d_ws + sz_hidden + sz_act);
    __half* wd16       = (__half*)((char*)d_ws + sz_hidden + sz_act + sz_wgu16);

    const size_t need_g1 = sz_hidden + sz_act + sz_wgu16;    // 109 MB
    const size_t need_g2 = need_g1 + sz_wd16;                // 132 MB (proven in r6)

    convert_hidden<<<dim3(TOKENS * HDIM / 8 / 256), dim3(256), 0, stream>>>(hidden, hidden_f16);

    if (ws_size >= need_g1) {
        dequant_wgu5<<<dim3(G1_NP / 256, 32), dim3(256), 0, stream>>>(wgu, sgu, wgu16);
        gemm1_s<<<dim3(G1_NP / BN, TOKENS / BM), dim3(256), 0, stream>>>(hidden_f16, wgu16, act);
    } else {
        gemm1_silu<<<dim3(IDIM / BN, TOKENS / BM), dim3(256), 0, stream>>>(hidden_f16, wgu, sgu, act);
    }

    if (ws_size >= need_g2) {
        dequant_wd5<<<dim3(HDIM / 256, IDIM / 64), dim3(256), 0, stream>>>(wd, sd, wd16);
        gemm2_s<<<dim3(HDIM / BN, TOKENS / BM), dim3(256), 0, stream>>>(act, wd16, moe, out);
    } else {
        gemm2_add<<<dim3(HDIM / BN, TOKENS / BM), dim3(256), 0, stream>>>(act, wd, sd, moe, out);
    }
}